// Round 1
// baseline (34.131 us; speedup 1.0000x reference)
//
#include <hip/hip_runtime.h>

// Problem constants (match reference: B=4, N=512, F_IN=F_OUT=128)
constexpr int B_    = 4;
constexpr int N_    = 512;
constexpr int F     = 128;     // F_IN == F_OUT
constexpr int R1    = 4;       // rows per block, kernel 1
constexpr int R2    = 4;       // node rows per block, kernel 2

// ---------------------------------------------------------------------------
// Kernel 1: xi = x @ Wi + b_msg ; xj = x @ Wj
// x: (B*N, F) row-major; W_msg: (2F, F) row-major.
// One block = R1 rows, 128 threads = one output column each.
// ---------------------------------------------------------------------------
__global__ __launch_bounds__(128) void k_gemm_msg(
    const float* __restrict__ x,
    const float* __restrict__ Wmsg,
    const float* __restrict__ bmsg,
    float* __restrict__ xi,
    float* __restrict__ xj)
{
    __shared__ float xs[R1][F];
    const int o  = threadIdx.x;          // output col 0..127
    const int r0 = blockIdx.x * R1;      // global row base

    #pragma unroll
    for (int r = 0; r < R1; ++r)
        xs[r][o] = x[(size_t)(r0 + r) * F + o];
    __syncthreads();

    float ai[R1] = {0.f, 0.f, 0.f, 0.f};
    float aj[R1] = {0.f, 0.f, 0.f, 0.f};

    #pragma unroll
    for (int f = 0; f < F; f += 4) {
        float4 xv[R1];
        #pragma unroll
        for (int r = 0; r < R1; ++r)
            xv[r] = *reinterpret_cast<const float4*>(&xs[r][f]);
        #pragma unroll
        for (int k = 0; k < 4; ++k) {
            const float wi = Wmsg[(size_t)(f + k) * F + o];
            const float wj = Wmsg[(size_t)(F + f + k) * F + o];
            #pragma unroll
            for (int r = 0; r < R1; ++r) {
                const float xvk = reinterpret_cast<const float*>(&xv[r])[k];
                ai[r] = fmaf(xvk, wi, ai[r]);
                aj[r] = fmaf(xvk, wj, aj[r]);
            }
        }
    }

    const float bm = bmsg[o];
    #pragma unroll
    for (int r = 0; r < R1; ++r) {
        xi[(size_t)(r0 + r) * F + o] = ai[r] + bm;  // bias folded into xi
        xj[(size_t)(r0 + r) * F + o] = aj[r];
    }
}

// ---------------------------------------------------------------------------
// Kernel 2: per block of R2 node rows (same batch):
//   phase 1: compact nonzero adj entries to LDS index/value lists
//   phase 2: agg[r][o] = sum_{j in list[r]} a * relu(xi[r][o] + xj[j][o])
//   phase 3: out[r][o] = relu( [x_row | agg_row] @ W_upd + b_upd )
// ---------------------------------------------------------------------------
__global__ __launch_bounds__(128) void k_agg_upd(
    const float* __restrict__ x,
    const float* __restrict__ adj,
    const float* __restrict__ xi,
    const float* __restrict__ xj,
    const float* __restrict__ Wupd,
    const float* __restrict__ bupd,
    float* __restrict__ out)
{
    __shared__ int   lst_j[R2][N_];
    __shared__ float lst_v[R2][N_];
    __shared__ int   cnt[R2];
    __shared__ float h[R2][2 * F];       // [x_row | agg_row]

    const int o  = threadIdx.x;
    const int rowsPerBatch = N_ / R2;    // blocks per batch
    const int b  = blockIdx.x / rowsPerBatch;
    const int i0 = (blockIdx.x % rowsPerBatch) * R2;

    if (o < R2) cnt[o] = 0;
    __syncthreads();

    // ---- phase 1: compaction (coalesced scan of R2 adj rows) + x row load
    const float* adjb = adj + ((size_t)b * N_ + i0) * N_;
    for (int t = o; t < R2 * N_; t += 128) {
        const int r = t >> 9;            // t / 512
        const int j = t & (N_ - 1);      // t % 512
        const float a = adjb[(size_t)r * N_ + j];
        if (a != 0.f) {
            const int p = atomicAdd(&cnt[r], 1);
            lst_j[r][p] = j;
            lst_v[r][p] = a;
        }
    }
    #pragma unroll
    for (int r = 0; r < R2; ++r)
        h[r][o] = x[((size_t)b * N_ + i0 + r) * F + o];
    __syncthreads();

    // ---- phase 2: sparse aggregate
    const float* xjb = xj + (size_t)b * N_ * F;
    #pragma unroll
    for (int r = 0; r < R2; ++r) {
        const float xir = xi[((size_t)b * N_ + i0 + r) * F + o];
        const int nn = cnt[r];
        float acc = 0.f;
        for (int k = 0; k < nn; ++k) {
            const int   j = lst_j[r][k];
            const float a = lst_v[r][k];
            const float v = xjb[(size_t)j * F + o];
            acc = fmaf(a, fmaxf(xir + v, 0.f), acc);
        }
        h[r][F + o] = acc;
    }
    __syncthreads();

    // ---- phase 3: update GEMM + relu
    float res[R2] = {0.f, 0.f, 0.f, 0.f};
    #pragma unroll
    for (int f = 0; f < 2 * F; f += 4) {
        float4 hv[R2];
        #pragma unroll
        for (int r = 0; r < R2; ++r)
            hv[r] = *reinterpret_cast<const float4*>(&h[r][f]);
        #pragma unroll
        for (int k = 0; k < 4; ++k) {
            const float w = Wupd[(size_t)(f + k) * F + o];
            #pragma unroll
            for (int r = 0; r < R2; ++r) {
                const float hk = reinterpret_cast<const float*>(&hv[r])[k];
                res[r] = fmaf(hk, w, res[r]);
            }
        }
    }

    const float bu = bupd[o];
    #pragma unroll
    for (int r = 0; r < R2; ++r)
        out[((size_t)b * N_ + i0 + r) * F + o] = fmaxf(res[r] + bu, 0.f);
}

// ---------------------------------------------------------------------------
extern "C" void kernel_launch(void* const* d_in, const int* in_sizes, int n_in,
                              void* d_out, int out_size, void* d_ws, size_t ws_size,
                              hipStream_t stream)
{
    const float* x    = (const float*)d_in[0];   // (B, N, F)
    const float* adj  = (const float*)d_in[1];   // (B, N, N)
    const float* Wmsg = (const float*)d_in[2];   // (2F, F)
    const float* bmsg = (const float*)d_in[3];   // (F,)
    const float* Wupd = (const float*)d_in[4];   // (2F, F)
    const float* bupd = (const float*)d_in[5];   // (F,)
    float* out = (float*)d_out;                  // (B, N, F)

    const size_t rows = (size_t)B_ * N_;         // 2048
    float* xi = (float*)d_ws;                    // rows*F floats = 1 MB
    float* xj = xi + rows * F;                   // 1 MB

    dim3 blk(128);
    k_gemm_msg<<<dim3(rows / R1), blk, 0, stream>>>(x, Wmsg, bmsg, xi, xj);
    k_agg_upd<<<dim3(rows / R2), blk, 0, stream>>>(x, adj, xi, xj, Wupd, bupd, out);
}

// Round 2
// 27.941 us; speedup vs baseline: 1.2215x; 1.2215x over previous
//
#include <hip/hip_runtime.h>

// Problem constants (reference: B=4, N=512, F_IN=F_OUT=128)
constexpr int B_   = 4;
constexpr int N_   = 512;
constexpr int F    = 128;
constexpr int R    = 4;     // rows per block (both kernels)
constexpr int LSTW = 520;   // per-row neighbor-list width (512 + pad, 16B-aligned stride)

// ---------------------------------------------------------------------------
// Kernel 1: xi = x @ Wi + b_msg ; xj = x @ Wj
// 256 threads: thread (h,o), h = K-half (64 k's each), o = output column.
// Partial sums combined through LDS. 512 blocks -> 8 waves/CU.
// ---------------------------------------------------------------------------
__global__ __launch_bounds__(256) void k_gemm_msg(
    const float* __restrict__ x,
    const float* __restrict__ Wmsg,
    const float* __restrict__ bmsg,
    float* __restrict__ xi,
    float* __restrict__ xj)
{
    __shared__ __align__(16) float xs[R][F];
    __shared__ float psI[2][R][F];
    __shared__ float psJ[2][R][F];

    const int t  = threadIdx.x;
    const int h  = t >> 7;            // K-half
    const int o  = t & 127;           // output column
    const int r0 = blockIdx.x * R;

    for (int idx = t; idx < R * F; idx += 256)
        xs[idx >> 7][idx & 127] = x[(size_t)r0 * F + idx];
    __syncthreads();

    float ai[R] = {0.f, 0.f, 0.f, 0.f};
    float aj[R] = {0.f, 0.f, 0.f, 0.f};
    const int kbase = h * 64;

    #pragma unroll
    for (int k = 0; k < 64; k += 4) {
        const int kk = kbase + k;
        float4 xv[R];
        #pragma unroll
        for (int r = 0; r < R; ++r)
            xv[r] = *reinterpret_cast<const float4*>(&xs[r][kk]);
        #pragma unroll
        for (int u = 0; u < 4; ++u) {
            const float wi = Wmsg[(size_t)(kk + u) * F + o];
            const float wj = Wmsg[(size_t)(F + kk + u) * F + o];
            #pragma unroll
            for (int r = 0; r < R; ++r) {
                const float xk = reinterpret_cast<const float*>(&xv[r])[u];
                ai[r] = fmaf(xk, wi, ai[r]);
                aj[r] = fmaf(xk, wj, aj[r]);
            }
        }
    }

    #pragma unroll
    for (int r = 0; r < R; ++r) { psI[h][r][o] = ai[r]; psJ[h][r][o] = aj[r]; }
    __syncthreads();

    if (h == 0) {
        const float bm = bmsg[o];
        #pragma unroll
        for (int r = 0; r < R; ++r) {
            xi[(size_t)(r0 + r) * F + o] = psI[0][r][o] + psI[1][r][o] + bm;
            xj[(size_t)(r0 + r) * F + o] = psJ[0][r][o] + psJ[1][r][o];
        }
    }
}

// ---------------------------------------------------------------------------
// Kernel 2 (per block of R node rows of one batch):
//   phase 1: deterministic ballot-compaction of adj rows (adj is exactly 0/1)
//   phase 2: agg[r][o] = sum_{j in list[r]} relu(xi[r][o] + xj[j][o]),
//            K-split across halves, 4-wide unrolled gathers (int4 index reads)
//   phase 3: out = relu([x | agg] @ W_upd + b_upd), K-split across halves
// 256 threads, no atomics -> fully deterministic.
// ---------------------------------------------------------------------------
__global__ __launch_bounds__(256) void k_agg_upd(
    const float* __restrict__ x,
    const float* __restrict__ adj,
    const float* __restrict__ xi,
    const float* __restrict__ xj,
    const float* __restrict__ Wupd,
    const float* __restrict__ bupd,
    float* __restrict__ out)
{
    __shared__ __align__(16) int lst[R][LSTW];
    __shared__ int   cnt[R], cntp[R];
    __shared__ float hrow[R][2 * F];      // [x_row | agg_row]
    __shared__ float part[2][R][F];

    const int t    = threadIdx.x;
    const int lane = t & 63;
    const int w    = t >> 6;              // wave id == row index for phase 1
    const int h    = t >> 7;              // K-half for phases 2/3
    const int o    = t & 127;
    const int rowsPerBatch = N_ / R;
    const int b  = blockIdx.x / rowsPerBatch;
    const int i0 = (blockIdx.x % rowsPerBatch) * R;

    // x rows into hrow[..][0..F)
    for (int idx = t; idx < R * F; idx += 256)
        hrow[idx >> 7][idx & 127] = x[((size_t)b * N_ + i0) * F + idx];

    // ---- phase 1: ballot compaction; wave w owns row w (ascending j order)
    {
        const float* arow = adj + ((size_t)b * N_ + i0 + w) * N_;
        int base = 0;
        #pragma unroll
        for (int s = 0; s < N_ / 64; ++s) {
            const int j = s * 64 + lane;
            const float a = arow[j];
            const unsigned long long m = __ballot(a != 0.f);
            const int off = __popcll(m & ((1ull << lane) - 1ull));
            if (a != 0.f) lst[w][base + off] = j;
            base += __popcll(m);
        }
        const int np = (base + 7) & ~7;
        if (lane < np - base) lst[w][base + lane] = 0;   // dummy (predicated off)
        if (lane == 0) { cnt[w] = base; cntp[w] = np; }
    }
    __syncthreads();

    // ---- phase 2: sparse aggregate, halves interleave 4-element chunks
    const float* xjb = xj + (size_t)b * N_ * F;
    #pragma unroll
    for (int r = 0; r < R; ++r) {
        const float xir = xi[((size_t)b * N_ + i0 + r) * F + o];
        const int nn = cnt[r], np = cntp[r];
        float acc = 0.f;
        for (int k = h * 4; k < np; k += 8) {
            const int4 id4 = *reinterpret_cast<const int4*>(&lst[r][k]);
            const float v0 = xjb[(size_t)id4.x * F + o];
            const float v1 = xjb[(size_t)id4.y * F + o];
            const float v2 = xjb[(size_t)id4.z * F + o];
            const float v3 = xjb[(size_t)id4.w * F + o];
            acc += (k + 0 < nn) ? fmaxf(xir + v0, 0.f) : 0.f;
            acc += (k + 1 < nn) ? fmaxf(xir + v1, 0.f) : 0.f;
            acc += (k + 2 < nn) ? fmaxf(xir + v2, 0.f) : 0.f;
            acc += (k + 3 < nn) ? fmaxf(xir + v3, 0.f) : 0.f;
        }
        part[h][r][o] = acc;
    }
    __syncthreads();
    if (h == 0) {
        #pragma unroll
        for (int r = 0; r < R; ++r)
            hrow[r][F + o] = part[0][r][o] + part[1][r][o];
    }
    __syncthreads();

    // ---- phase 3: update GEMM + relu, K-split across halves
    float res[R] = {0.f, 0.f, 0.f, 0.f};
    const int kb = h * F;
    #pragma unroll
    for (int k = 0; k < F; k += 4) {
        #pragma unroll
        for (int u = 0; u < 4; ++u) {
            const int kk = kb + k + u;
            const float wv = Wupd[(size_t)kk * F + o];
            #pragma unroll
            for (int r = 0; r < R; ++r)
                res[r] = fmaf(hrow[r][kk], wv, res[r]);
        }
    }
    #pragma unroll
    for (int r = 0; r < R; ++r) part[h][r][o] = res[r];
    __syncthreads();

    if (h == 0) {
        const float bu = bupd[o];
        #pragma unroll
        for (int r = 0; r < R; ++r)
            out[((size_t)b * N_ + i0 + r) * F + o] =
                fmaxf(part[0][r][o] + part[1][r][o] + bu, 0.f);
    }
}

// ---------------------------------------------------------------------------
extern "C" void kernel_launch(void* const* d_in, const int* in_sizes, int n_in,
                              void* d_out, int out_size, void* d_ws, size_t ws_size,
                              hipStream_t stream)
{
    const float* x    = (const float*)d_in[0];
    const float* adj  = (const float*)d_in[1];
    const float* Wmsg = (const float*)d_in[2];
    const float* bmsg = (const float*)d_in[3];
    const float* Wupd = (const float*)d_in[4];
    const float* bupd = (const float*)d_in[5];
    float* out = (float*)d_out;

    const size_t rows = (size_t)B_ * N_;       // 2048
    float* xi = (float*)d_ws;                  // 1 MB
    float* xj = xi + rows * F;                 // 1 MB

    k_gemm_msg<<<dim3(rows / R), dim3(256), 0, stream>>>(x, Wmsg, bmsg, xi, xj);
    k_agg_upd<<<dim3(rows / R), dim3(256), 0, stream>>>(x, adj, xi, xj, Wupd, bupd, out);
}